// Round 7
// baseline (225.079 us; speedup 1.0000x reference)
//
#include <hip/hip_runtime.h>
#include <hip/hip_bf16.h>
#include <cstdint>

#define B_ 16
#define S_ 2048
#define H_ 1024
#define D_ 64
#define R_ 2048
#define M_ (B_*S_)   // 32768 rows
#define N_ 128       // 2*D
#define NC_ 16       // K chunks of 64

typedef short short8 __attribute__((ext_vector_type(8)));
typedef float f32x4  __attribute__((ext_vector_type(4)));

__device__ __forceinline__ unsigned short f2bf(float f) {
    unsigned u = __builtin_bit_cast(unsigned, f);
    u += 0x7FFFu + ((u >> 16) & 1u);     // RNE
    return (unsigned short)(u >> 16);
}
__device__ __forceinline__ unsigned pk2(float a, float b) {      // RNE pack
    return (unsigned)f2bf(a) | ((unsigned)f2bf(b) << 16);
}
__device__ __forceinline__ unsigned pkt(float a, float b) {      // trunc pack
    return (__builtin_bit_cast(unsigned, a) >> 16) |
           (__builtin_bit_cast(unsigned, b) & 0xFFFF0000u);
}
__device__ __forceinline__ float bflo(unsigned u) {
    return __builtin_bit_cast(float, u << 16);
}
__device__ __forceinline__ float bfhi(unsigned u) {
    return __builtin_bit_cast(float, u & 0xFFFF0000u);
}

// ---------------------------------------------------------------------------
// Kernel 0: Wt[n][k] = bf16(W[k][n]) via coalesced LDS transpose.
// ---------------------------------------------------------------------------
__global__ void build_wt(const float* __restrict__ W, unsigned short* __restrict__ Wt) {
    __shared__ unsigned short lt[N_ * 34];
    const int t  = threadIdx.x;
    const int bk = blockIdx.x;
    const int kr = t >> 7, cn = t & 127;
    #pragma unroll
    for (int i = 0; i < 16; i++) {
        const int k = i * 2 + kr;
        lt[cn * 34 + k] = f2bf(W[(size_t)(bk * 32 + k) * N_ + cn]);
    }
    __syncthreads();
    const int kk = t & 31, nr = t >> 5;
    #pragma unroll
    for (int i = 0; i < 16; i++) {
        const int n = i * 8 + nr;
        Wt[(size_t)n * H_ + bk * 32 + kk] = lt[n * 34 + kk];
    }
}

// ---------------------------------------------------------------------------
// Kernel 1: GEMM + RoPE. Block = 128 thr = 2 waves; wave = 16 rows x 128
// cols (8 MFMA col-tiles). A-frags load DIRECT global->VGPR: lane (ln15,
// quad) reads exactly A[row=ln15][quad*8..+8] (32 B private, zero waste,
// A read exactly once, no LDS round-trip). Only W (16 KB/chunk) is LDS-
// staged, double-buffered, 16B-granule XOR swizzle. Both A and W carry
// 2-chunk register lookahead, so the per-chunk barrier drains only LDS
// writes whose sources are long since resident. LDS = 32 KB -> 4 blocks/CU;
// grid 1024 = exactly one residency round, 8 waves/CU.
// ---------------------------------------------------------------------------
__launch_bounds__(128, 2)
__global__ void gemm_rope(const float* __restrict__ A,            // [M][1024]
                          const unsigned short* __restrict__ Wt,  // [128][1024] bf16
                          const float* __restrict__ bias,         // [128]
                          const int* __restrict__ pos_ids,        // [M]
                          unsigned* __restrict__ qk)              // [M][64] bf16x2
{
    __shared__ __align__(16) unsigned short wbuf[2][N_ * 64];     // 2 x 16 KiB

    const int tid  = threadIdx.x;
    const int wv   = tid >> 6, lane = tid & 63;
    const int ln15 = lane & 15, quad = lane >> 4, key = ln15 & 7;
    const int m0   = blockIdx.x * 32;
    const int row  = m0 + wv * 16 + ln15;

    const float* a_base = A + (size_t)row * H_ + quad * 8;

    // ---- W staging map: 8 units of 16B per thread, fully coalesced reads
    const unsigned short* w_src[8]; int w_dst[8];
    #pragma unroll
    for (int i = 0; i < 8; i++) {
        const int u = i * 128 + tid;
        const int n = u >> 3, oc = u & 7;
        w_src[i] = Wt + (size_t)n * H_ + oc * 8;
        w_dst[i] = n * 64 + ((oc ^ (n & 7)) * 8);
    }

    f32x4  areg[2][4];    // chunk c lives in areg[c&1]; [ks*2+half]
    short8 wreg[2][8];    // chunk c lives in wreg[c&1]
    f32x4  acc[8];
    #pragma unroll
    for (int j = 0; j < 8; j++) acc[j] = (f32x4)0.f;

    // ---- prologue: A(0)->areg[0], A(1)->areg[1]; W(0)->LDS; W(1)->wreg[1]
    #pragma unroll
    for (int ks = 0; ks < 2; ks++)
        #pragma unroll
        for (int h = 0; h < 2; h++) {
            areg[0][ks * 2 + h] = *(const f32x4*)(a_base + ks * 32 + h * 4);
            areg[1][ks * 2 + h] = *(const f32x4*)(a_base + 64 + ks * 32 + h * 4);
        }
    #pragma unroll
    for (int i = 0; i < 8; i++) wreg[0][i] = *(const short8*)(w_src[i]);
    #pragma unroll
    for (int i = 0; i < 8; i++) *(short8*)(&wbuf[0][w_dst[i]]) = wreg[0][i];
    #pragma unroll
    for (int i = 0; i < 8; i++) wreg[1][i] = *(const short8*)(w_src[i] + 64);

    #pragma unroll
    for (int kc = 0; kc < NC_; kc++) {
        const int cb = kc & 1, nb = cb ^ 1;
        __syncthreads();                     // readers of wbuf[nb] (chunk kc-1) done
        if (kc + 1 < NC_) {                  // write chunk kc+1 (regs -> LDS)
            #pragma unroll
            for (int i = 0; i < 8; i++)
                *(short8*)(&wbuf[nb][w_dst[i]]) = wreg[nb][i];
        }
        // ---- pack this chunk's A-frags, then refill both lookaheads (kc+2)
        short8 af[2];
        #pragma unroll
        for (int ks = 0; ks < 2; ks++) {
            const f32x4 r0 = areg[cb][ks * 2 + 0];
            const f32x4 r1 = areg[cb][ks * 2 + 1];
            int4 p;
            p.x = (int)pkt(r0[0], r0[1]);
            p.y = (int)pkt(r0[2], r0[3]);
            p.z = (int)pkt(r1[0], r1[1]);
            p.w = (int)pkt(r1[2], r1[3]);
            af[ks] = __builtin_bit_cast(short8, p);
        }
        if (kc + 2 < NC_) {
            const int o = (kc + 2) * 64;
            #pragma unroll
            for (int ks = 0; ks < 2; ks++)
                #pragma unroll
                for (int h = 0; h < 2; h++)
                    areg[cb][ks * 2 + h] = *(const f32x4*)(a_base + o + ks * 32 + h * 4);
            #pragma unroll
            for (int i = 0; i < 8; i++)
                wreg[cb][i] = *(const short8*)(w_src[i] + o);
        }
        // ---- compute chunk kc from wbuf[cb]
        #pragma unroll
        for (int ks = 0; ks < 2; ks++) {
            const int g = ((ks * 4 + quad) ^ key) * 8;
            #pragma unroll
            for (int j = 0; j < 8; j++) {
                const short8 bf = *(const short8*)(&wbuf[cb][(j * 16 + ln15) * 64 + g]);
                acc[j] = __builtin_amdgcn_mfma_f32_16x16x32_bf16(af[ks], bf, acc[j], 0, 0, 0);
            }
        }
    }

    // ---- epilogue: bias + RoPE + packed bf16 store
    // C/D layout: col(within tile j) = ln15, row = quad*4 + reg
    float bv[8], invr[4];
    #pragma unroll
    for (int j = 0; j < 8; j++) bv[j] = bias[j * 16 + ln15];
    #pragma unroll
    for (int j = 0; j < 4; j++) {
        const float fi = (float)((j * 16 + ln15) >> 1);          // freq idx in half
        invr[j] = exp2f(fi * -0.41524101186092029f) * 0.15915494309189535f;
    }
    const bool odd = (ln15 & 1);
    const int rbase = m0 + wv * 16 + quad * 4;
    #pragma unroll
    for (int reg = 0; reg < 4; reg++) {
        const int r = rbase + reg;
        const float pos = (float)pos_ids[r];
        #pragma unroll
        for (int j = 0; j < 8; j++) {
            float v = acc[j][reg] + bv[j];
            float p = __shfl_xor(v, 1, 64);                      // partner col c^1
            float fr = __builtin_amdgcn_fractf(pos * invr[j & 3]);
            float s  = __builtin_amdgcn_sinf(fr);
            float co = __builtin_amdgcn_cosf(fr);
            float outv = odd ? fmaf(v, co, p * s) : fmaf(v, co, -p * s);
            float po = __shfl_xor(outv, 1, 64);
            if (!odd)
                qk[(size_t)r * 64 + j * 8 + (ln15 >> 1)] = pk2(outv, po);
        }
    }
}

// ---------------------------------------------------------------------------
// Kernel 2: one wave per relation; qk is packed bf16 pairs.
// lanes 0..31: qw[i0] . kw[i2];  lanes 32..63: qw[i1] . kw[i3]
// ---------------------------------------------------------------------------
__global__ void gather_dot(const unsigned* __restrict__ qk, const int* __restrict__ rel,
                           const float* __restrict__ mask, float* __restrict__ out)
{
    const int w    = (blockIdx.x * 256 + threadIdx.x) >> 6;   // 0..32767
    const int lane = threadIdx.x & 63;
    const int b    = w >> 11;
    const int4 id4 = ((const int4*)rel)[w];
    const unsigned* base = qk + (size_t)b * S_ * 64;
    const int rq  = (lane < 32) ? id4.x : id4.y;
    const int rk  = (lane < 32) ? id4.z : id4.w;
    const int col = lane & 31;
    const unsigned uq = base[(size_t)rq * 64 + col];
    const unsigned uk = base[(size_t)rk * 64 + 32 + col];
    float v = bflo(uq) * bflo(uk) + bfhi(uq) * bfhi(uk);
    #pragma unroll
    for (int off = 32; off; off >>= 1) v += __shfl_xor(v, off, 64);
    if (lane == 0)
        out[w] = (v + (1.0f - mask[w]) * -1e12f) * 0.125f;
}

// ---------------------------------------------------------------------------
extern "C" void kernel_launch(void* const* d_in, const int* in_sizes, int n_in,
                              void* d_out, int out_size, void* d_ws, size_t ws_size,
                              hipStream_t stream) {
    const float* lhs  = (const float*)d_in[0];   // (B,S,H) fp32
    const float* W    = (const float*)d_in[1];   // (H,128) fp32
    const float* bias = (const float*)d_in[2];   // (128,)  fp32
    const int*   pos  = (const int*)d_in[3];     // (B,S)   int32
    const int*   rel  = (const int*)d_in[4];     // (B,R,4) int32
    const float* mask = (const float*)d_in[5];   // (B,R)   fp32
    float* out = (float*)d_out;                  // (B,R)   fp32

    unsigned short* Wt = (unsigned short*)d_ws;                      // 256 KiB
    unsigned* qk = (unsigned*)((char*)d_ws + (size_t)N_ * H_ * 2);   // 8 MiB bf16 pairs

    build_wt<<<32, 256, 0, stream>>>(W, Wt);
    gemm_rope<<<1024, 128, 0, stream>>>(lhs, Wt, bias, pos, qk);
    gather_dot<<<8192, 256, 0, stream>>>(qk, rel, mask, out);
}